// Round 2
// baseline (433.542 us; speedup 1.0000x reference)
//
#include <hip/hip_runtime.h>

typedef __attribute__((ext_vector_type(8))) __bf16 bf16x8;
typedef __attribute__((ext_vector_type(4))) __bf16 bf16x4;
typedef __attribute__((ext_vector_type(4))) float f32x4;

constexpr int kB = 8, kN = 8192, kE = 65536;
constexpr int kBN = kB * kN;    // 65536 nodes total
constexpr int kBE = kB * kE;    // 524288 edges total
constexpr int kDN = 64, kDE = 64, kIU = 128;

constexpr int XS = 200;  // X row stride in bf16 (192 + 8 pad)
constexpr int HS = 136;  // H row stride (128 + 8)
constexpr int ES = 72;   // E row stride (64 + 8)

// LDS-only barrier: leaves global loads/stores/atomics outstanding across it.
__device__ __forceinline__ void lds_barrier() {
    asm volatile("s_waitcnt lgkmcnt(0)\n\ts_barrier" ::: "memory");
}

// Packed bf16x2 atomic add (device scope via sc1). addr first, data second.
__device__ __forceinline__ void atomic_pk_add_bf16(__bf16* p, uint32_t pk) {
    const unsigned long long a64 = (unsigned long long)p;
    asm volatile("global_atomic_pk_add_bf16 %0, %1, off sc1"
                 :: "v"(a64), "v"(pk) : "memory");
}

// ---------------------------------------------------------------------------
// Pre-pass: cast fp32 node table -> bf16 table (halves gather bytes + L2
// footprint; removes fp32->bf16 cvt from the hot staging loop).
// The bf16 table lives in the (dead until finalize) nodes_new output region —
// NOT in d_ws, whose 8.25 MiB layout stays identical to the passing baseline.
// ---------------------------------------------------------------------------
__global__ __launch_bounds__(256)
void cast_nodes(const float* __restrict__ nodes, __bf16* __restrict__ nbf) {
    const int t = blockIdx.x * 256 + threadIdx.x;      // < kBN*kDN/8
    const float4* nf = (const float4*)nodes;
    const float4 a = nf[t * 2];
    const float4 c = nf[t * 2 + 1];
    bf16x8 o = {(__bf16)a.x, (__bf16)a.y, (__bf16)a.z, (__bf16)a.w,
                (__bf16)c.x, (__bf16)c.y, (__bf16)c.z, (__bf16)c.w};
    ((bf16x8*)nbf)[t] = o;
}

// ---------------------------------------------------------------------------
// Fused edge MLP: gather -> L1 -> L2 (e_new) -> L3 (edges_out)
//   Node gathers come from the bf16 table (128 B/row). Two-slot software
//   pipeline gives gathers ~2 tile-phases of lead before consumption.
// ---------------------------------------------------------------------------

// Gather one tile into a register slot (node rows as bf16x8, edges fp32).
#define GATHER(Rr, Sr, Ee, tg, rv, sv) do {                                   \
    const int g_ = (tg) * 64 + row;                                           \
    const int b_ = g_ >> 16;                                                  \
    const int rg_ = ((rv) < 0) ? (kBN - 1) : (rv) + (b_ << 13);               \
    const int sg_ = ((sv) < 0) ? (kBN - 1) : (sv) + (b_ << 13);               \
    const bf16x8* nb_ = (const bf16x8*)nbf;                                   \
    Rr[0] = nb_[rg_ * 8 + qt * 2];  Rr[1] = nb_[rg_ * 8 + qt * 2 + 1];        \
    Sr[0] = nb_[sg_ * 8 + qt * 2];  Sr[1] = nb_[sg_ * 8 + qt * 2 + 1];        \
    const float4* ez_ = (const float4*)edges + (size_t)g_ * 16;               \
    Ee[0] = ez_[qt];  Ee[1] = ez_[qt + 4];                                    \
    Ee[2] = ez_[qt + 8];  Ee[3] = ez_[qt + 12];                               \
} while (0)

// Stage a gathered slot into Xs + per-edge side effects.
#define STAGE(Rr, Sr, Ee, tg, rv, sv, bufi) do {                              \
    const int g_ = (tg) * 64 + row;                                           \
    const int b_ = g_ >> 16;                                                  \
    const int rs_ = ((rv) < 0) ? -1 : (rv) + (b_ << 13);                      \
    if (qt == 0) {                                                            \
        rsS[bufi][row] = rs_;                                                 \
        out_sf[g_] = (float)(sv);                                             \
        out_rf[g_] = (float)(rv);                                             \
        if (rs_ >= 0) atomicAdd(&counts[rs_], 1.0f);                          \
    }                                                                         \
    __bf16* xr_ = &Xs_[row * XS];                                             \
    /* recv/send: pure b128 copies; bank group (row+2qt)%8 -> conflict-free */\
    *(bf16x8*)&xr_[qt * 16]           = Rr[0];                                \
    *(bf16x8*)&xr_[qt * 16 + 8]       = Rr[1];                                \
    *(bf16x8*)&xr_[128 + qt * 16]     = Sr[0];                                \
    *(bf16x8*)&xr_[128 + qt * 16 + 8] = Sr[1];                                \
    _Pragma("unroll")                                                         \
    for (int i_ = 0; i_ < 4; ++i_) {                                          \
        float4 e_ = Ee[i_];                                                   \
        *(bf16x4*)&xr_[64 + 4 * qt + 16 * i_] =                               \
            (bf16x4){(__bf16)e_.x, (__bf16)e_.y, (__bf16)e_.z, (__bf16)e_.w}; \
    }                                                                         \
} while (0)

// Full per-tile compute: L1 -> B2 -> L2 -> B3 -> L3 + scatter.
#define COMPUTE(tg, bufi) do {                                                \
    const int g0_ = (tg) * 64;                                                \
    _Pragma("unroll")                                                         \
    for (int m_ = 0; m_ < 4; ++m_) {                                          \
        const __bf16* ar_ = &Xs_[(m_ * 16 + c16) * XS + q * 8];               \
        bf16x8 a_[6];                                                         \
        _Pragma("unroll")                                                     \
        for (int kk_ = 0; kk_ < 6; ++kk_)                                     \
            a_[kk_] = *(const bf16x8*)(ar_ + kk_ * 32);                       \
        f32x4 acc0_ = (f32x4){0.f, 0.f, 0.f, 0.f};                            \
        f32x4 acc1_ = (f32x4){0.f, 0.f, 0.f, 0.f};                            \
        _Pragma("unroll")                                                     \
        for (int kk_ = 0; kk_ < 6; ++kk_)                                     \
            acc0_ = __builtin_amdgcn_mfma_f32_16x16x32_bf16(a_[kk_], winf[kk_][0], acc0_, 0, 0, 0); \
        _Pragma("unroll")                                                     \
        for (int kk_ = 0; kk_ < 6; ++kk_)                                     \
            acc1_ = __builtin_amdgcn_mfma_f32_16x16x32_bf16(a_[kk_], winf[kk_][1], acc1_, 0, 0, 0); \
        _Pragma("unroll")                                                     \
        for (int r_ = 0; r_ < 4; ++r_) {                                      \
            __bf16* hr_ = &Hs_[(m_ * 16 + q * 4 + r_) * HS + wave * 32];      \
            hr_[c16]      = (__bf16)fmaxf(acc0_[r_] + bin0, 0.f);             \
            hr_[16 + c16] = (__bf16)fmaxf(acc1_[r_] + bin1, 0.f);             \
        }                                                                     \
    }                                                                         \
    lds_barrier();   /* B2: H ready */                                        \
    _Pragma("unroll")                                                         \
    for (int m_ = 0; m_ < 4; ++m_) {                                          \
        const __bf16* ar_ = &Hs_[(m_ * 16 + c16) * HS + q * 8];               \
        bf16x8 a_[4];                                                         \
        _Pragma("unroll")                                                     \
        for (int kk_ = 0; kk_ < 4; ++kk_)                                     \
            a_[kk_] = *(const bf16x8*)(ar_ + kk_ * 32);                       \
        f32x4 acc_ = (f32x4){0.f, 0.f, 0.f, 0.f};                             \
        _Pragma("unroll")                                                     \
        for (int kk_ = 0; kk_ < 4; ++kk_)                                     \
            acc_ = __builtin_amdgcn_mfma_f32_16x16x32_bf16(a_[kk_], woutf[kk_], acc_, 0, 0, 0); \
        _Pragma("unroll")                                                     \
        for (int r_ = 0; r_ < 4; ++r_)                                        \
            Es_[(m_ * 16 + q * 4 + r_) * ES + wave * 16 + c16] =              \
                (__bf16)fmaxf(acc_[r_] + bo, 0.f);                            \
    }                                                                         \
    lds_barrier();   /* B3: E ready */                                        \
    _Pragma("unroll")                                                         \
    for (int m_ = 0; m_ < 4; ++m_) {                                          \
        const __bf16* ar_ = &Es_[(m_ * 16 + c16) * ES + q * 8];               \
        bf16x8 a0_ = *(const bf16x8*)ar_;                                     \
        bf16x8 a1_ = *(const bf16x8*)(ar_ + 32);                              \
        f32x4 acc_ = (f32x4){0.f, 0.f, 0.f, 0.f};                             \
        acc_ = __builtin_amdgcn_mfma_f32_16x16x32_bf16(a0_, wedgef[0], acc_, 0, 0, 0); \
        acc_ = __builtin_amdgcn_mfma_f32_16x16x32_bf16(a1_, wedgef[1], acc_, 0, 0, 0); \
        _Pragma("unroll")                                                     \
        for (int r_ = 0; r_ < 4; ++r_)                                        \
            edges_out[(size_t)(g0_ + m_ * 16 + q * 4 + r_) * kDE + wave * 16 + c16] = \
                fmaxf(acc_[r_] + beg, 0.f);                                   \
    }                                                                         \
    {                                                                         \
        const int half_ = lane >> 5;                                          \
        const int pc_   = lane & 31;                                          \
        _Pragma("unroll")                                                     \
        for (int i_ = 0; i_ < 8; ++i_) {                                      \
            const int rr_ = wave * 16 + half_ * 8 + i_;                       \
            const int rs2_ = rsS[bufi][rr_];                                  \
            if (rs2_ >= 0) {                                                  \
                const uint32_t pk_ = *(const uint32_t*)&Es_[rr_ * ES + pc_ * 2]; \
                atomic_pk_add_bf16(sums + (size_t)rs2_ * kDN + pc_ * 2, pk_); \
            }                                                                 \
        }                                                                     \
    }                                                                         \
} while (0)

__global__ __launch_bounds__(256, 3)
void edge_mlp_pk(const __bf16* __restrict__ nbf,
                 const float* __restrict__ edges,
                 const int* __restrict__ senders,
                 const int* __restrict__ receivers,
                 const float* __restrict__ W_in,
                 const float* __restrict__ b_in,
                 const float* __restrict__ W_out,
                 const float* __restrict__ b_out,
                 const float* __restrict__ W_edge,
                 const float* __restrict__ b_edge,
                 float* __restrict__ edges_out,
                 float* __restrict__ out_sf,
                 float* __restrict__ out_rf,
                 __bf16* __restrict__ sums,     // [kBN][64] bf16
                 float* __restrict__ counts)    // [kBN] fp32
{
    __shared__ alignas(16) __bf16 Xs_[64 * XS];
    __shared__ alignas(16) __bf16 Hs_[64 * HS];
    __shared__ alignas(16) __bf16 Es_[64 * ES];
    __shared__ int rsS[2][64];

    const int tid  = threadIdx.x;
    const int lane = tid & 63;
    const int wave = tid >> 6;
    const int c16  = lane & 15;
    const int q    = lane >> 4;

    // ---- weight B-fragments in registers (loaded once per block) ----
    bf16x8 winf[6][2];
#pragma unroll
    for (int kk = 0; kk < 6; ++kk)
#pragma unroll
        for (int nt = 0; nt < 2; ++nt)
#pragma unroll
            for (int j = 0; j < 8; ++j)
                winf[kk][nt][j] =
                    (__bf16)W_in[(kk * 32 + q * 8 + j) * kIU + wave * 32 + nt * 16 + c16];
    bf16x8 woutf[4];
#pragma unroll
    for (int kk = 0; kk < 4; ++kk)
#pragma unroll
        for (int j = 0; j < 8; ++j)
            woutf[kk][j] = (__bf16)W_out[(kk * 32 + q * 8 + j) * kDN + wave * 16 + c16];
    bf16x8 wedgef[2];
#pragma unroll
    for (int kk = 0; kk < 2; ++kk)
#pragma unroll
        for (int j = 0; j < 8; ++j)
            wedgef[kk][j] = (__bf16)W_edge[(kk * 32 + q * 8 + j) * kDE + wave * 16 + c16];

    const float bin0 = b_in[wave * 32 + c16];
    const float bin1 = b_in[wave * 32 + 16 + c16];
    const float bo   = b_out[wave * 16 + c16];
    const float beg  = b_edge[wave * 16 + c16];

    const int row = tid >> 2;   // edge row within tile
    const int qt  = tid & 3;    // column-quarter owner
    constexpr int ntiles = kBE / 64;
    const int S = gridDim.x;

    // ---- two gather slots: 2 tiles of memory-latency lead ----
    bf16x8 R0[2], Sd0[2]; float4 E0[4]; int rV0, sV0;
    bf16x8 R1[2], Sd1[2]; float4 E1[4]; int rV1, sV1;
    int rI = 0, sI = 0;

    const int t0 = blockIdx.x;
    {
        const int g = t0 * 64 + row;
        rV0 = receivers[g]; sV0 = senders[g];
    }
    if (t0 + S < ntiles) {
        const int g = (t0 + S) * 64 + row;
        rV1 = receivers[g]; sV1 = senders[g];
    } else { rV1 = 0; sV1 = 0; }
    GATHER(R0, Sd0, E0, t0, rV0, sV0);
    if (t0 + S < ntiles) GATHER(R1, Sd1, E1, t0 + S, rV1, sV1);
    if (t0 + 2 * S < ntiles) {
        const int g = (t0 + 2 * S) * 64 + row;
        rI = receivers[g]; sI = senders[g];
    }

    for (int t = t0; t < ntiles; t += 2 * S) {
        // ---- body A: slot0 / buf0 ----
        STAGE(R0, Sd0, E0, t, rV0, sV0, 0);
        lds_barrier();   // B1: X ready
        if (t + 2 * S < ntiles) {
            GATHER(R0, Sd0, E0, t + 2 * S, rI, sI);
            rV0 = rI; sV0 = sI;
        }
        if (t + 3 * S < ntiles) {
            const int g = (t + 3 * S) * 64 + row;
            rI = receivers[g]; sI = senders[g];
        }
        COMPUTE(t, 0);

        // ---- body B: slot1 / buf1 ----
        const int tB = t + S;
        if (tB < ntiles) {
            STAGE(R1, Sd1, E1, tB, rV1, sV1, 1);
            lds_barrier();   // B1: X ready
            if (t + 3 * S < ntiles) {
                GATHER(R1, Sd1, E1, t + 3 * S, rI, sI);
                rV1 = rI; sV1 = sI;
            }
            if (t + 4 * S < ntiles) {
                const int g = (t + 4 * S) * 64 + row;
                rI = receivers[g]; sI = senders[g];
            }
            COMPUTE(tB, 1);
        }
    }
}

// nodes_new = counts>0 ? bf16sums/counts : 0  (1 thread = 4 columns)
__global__ __launch_bounds__(256)
void finalize_kernel(const unsigned int* __restrict__ sums_u32,  // 2 bf16 per u32
                     const float* __restrict__ counts,
                     float* __restrict__ out)
{
    const int t = blockIdx.x * blockDim.x + threadIdx.x;   // < kBN*kDN/4
    const unsigned int p0 = sums_u32[t * 2];
    const unsigned int p1 = sums_u32[t * 2 + 1];
    const float c = counts[t >> 4];
    float4 o;
    if (c > 0.f) {
        const float inv = 1.f / c;
        union { unsigned int u; float f; } v;
        v.u = p0 << 16;            o.x = v.f * inv;
        v.u = p0 & 0xffff0000u;    o.y = v.f * inv;
        v.u = p1 << 16;            o.z = v.f * inv;
        v.u = p1 & 0xffff0000u;    o.w = v.f * inv;
    } else {
        o.x = o.y = o.z = o.w = 0.f;
    }
    ((float4*)out)[t] = o;
}

extern "C" void kernel_launch(void* const* d_in, const int* in_sizes, int n_in,
                              void* d_out, int out_size, void* d_ws, size_t ws_size,
                              hipStream_t stream) {
    const float* nodes     = (const float*)d_in[0];
    const float* edges     = (const float*)d_in[1];
    const int*   senders   = (const int*)d_in[2];
    const int*   receivers = (const int*)d_in[3];
    const float* W_in      = (const float*)d_in[4];
    const float* b_in      = (const float*)d_in[5];
    const float* W_out     = (const float*)d_in[6];
    const float* b_out     = (const float*)d_in[7];
    const float* W_edge    = (const float*)d_in[8];
    const float* b_edge    = (const float*)d_in[9];

    float* out       = (float*)d_out;
    float* edges_out = out + (size_t)kBN * kDN;
    float* out_sf    = edges_out + (size_t)kBE * kDE;
    float* out_rf    = out_sf + kBE;

    // ws: bf16 sums [8 MiB] | fp32 counts [256 KiB]   (identical to baseline)
    __bf16* sums  = (__bf16*)d_ws;
    float* counts = (float*)((char*)d_ws + (size_t)kBN * kDN * 2);

    // bf16 node table (8 MiB) lives in the nodes_new output region (16 MiB),
    // which is dead until finalize_kernel overwrites it at the end.
    __bf16* nbf = (__bf16*)out;

    hipMemsetAsync(d_ws, 0, (size_t)kBN * kDN * 2 + (size_t)kBN * 4, stream);

    cast_nodes<<<kBN * kDN / 8 / 256, 256, 0, stream>>>(nodes, nbf);

    edge_mlp_pk<<<2048, 256, 0, stream>>>(
        nbf, edges, senders, receivers,
        W_in, b_in, W_out, b_out, W_edge, b_edge,
        edges_out, out_sf, out_rf, sums, counts);

    finalize_kernel<<<kBN * kDN / 4 / 256, 256, 0, stream>>>(
        (const unsigned int*)sums, counts, out);
}

// Round 3
// 335.287 us; speedup vs baseline: 1.2931x; 1.2931x over previous
//
#include <hip/hip_runtime.h>

typedef __attribute__((ext_vector_type(8))) __bf16 bf16x8;
typedef __attribute__((ext_vector_type(4))) __bf16 bf16x4;
typedef __attribute__((ext_vector_type(4))) float f32x4;

constexpr int kB = 8, kN = 8192, kE = 65536;
constexpr int kBN = kB * kN;    // 65536 nodes total
constexpr int kBE = kB * kE;    // 524288 edges total
constexpr int kDN = 64, kDE = 64, kIU = 128;

constexpr int XS = 200;  // X row stride in bf16 (192 + 8 pad)
constexpr int HS = 136;  // H row stride (128 + 8)
constexpr int ES = 72;   // E row stride (64 + 8)

// LDS-only barrier: leaves global loads/stores/atomics outstanding across it.
__device__ __forceinline__ void lds_barrier() {
    asm volatile("s_waitcnt lgkmcnt(0)\n\ts_barrier" ::: "memory");
}

// Packed bf16x2 atomic add (device scope via sc1). addr first, data second.
__device__ __forceinline__ void atomic_pk_add_bf16(__bf16* p, uint32_t pk) {
    const unsigned long long a64 = (unsigned long long)p;
    asm volatile("global_atomic_pk_add_bf16 %0, %1, off sc1"
                 :: "v"(a64), "v"(pk) : "memory");
}

// ---------------------------------------------------------------------------
// Pre-pass: cast fp32 node table -> bf16 (halves gather bytes + L2 footprint;
// removes fp32->bf16 cvt from hot staging). Table lives in the nodes_new
// output region (dead until finalize_kernel); d_ws layout = baseline 8.25 MiB.
// ---------------------------------------------------------------------------
__global__ __launch_bounds__(256)
void cast_nodes(const float* __restrict__ nodes, __bf16* __restrict__ nbf) {
    const int t = blockIdx.x * 256 + threadIdx.x;      // < kBN*kDN/8
    const float4* nf = (const float4*)nodes;
    const float4 a = nf[t * 2];
    const float4 c = nf[t * 2 + 1];
    bf16x8 o = {(__bf16)a.x, (__bf16)a.y, (__bf16)a.z, (__bf16)a.w,
                (__bf16)c.x, (__bf16)c.y, (__bf16)c.z, (__bf16)c.w};
    ((bf16x8*)nbf)[t] = o;
}

// ---------------------------------------------------------------------------
// Fused edge MLP: gather -> L1 -> L2 (e_new) -> L3 (edges_out)
//   e_new scattered into bf16 sums table via packed-bf16 atomics (2 cols/op).
//   counts via fp32 atomics (1/edge). sf/rf float casts fused here too.
//   Structure identical to the 172 us baseline (1-deep gather prefetch);
//   ONLY the node gathers changed fp32->bf16 (48->32 slot VGPRs).
// ---------------------------------------------------------------------------
__global__ __launch_bounds__(256, 3)
void edge_mlp_pk(const __bf16* __restrict__ nbf,
                 const float* __restrict__ edges,
                 const int* __restrict__ senders,
                 const int* __restrict__ receivers,
                 const float* __restrict__ W_in,
                 const float* __restrict__ b_in,
                 const float* __restrict__ W_out,
                 const float* __restrict__ b_out,
                 const float* __restrict__ W_edge,
                 const float* __restrict__ b_edge,
                 float* __restrict__ edges_out,
                 float* __restrict__ out_sf,
                 float* __restrict__ out_rf,
                 __bf16* __restrict__ sums,     // [kBN][64] bf16
                 float* __restrict__ counts)    // [kBN] fp32
{
    __shared__ alignas(16) __bf16 Xs_[64 * XS];
    __shared__ alignas(16) __bf16 Hs_[64 * HS];
    __shared__ alignas(16) __bf16 Es_[64 * ES];
    __shared__ int rsS[2][64];

    const int tid  = threadIdx.x;
    const int lane = tid & 63;
    const int wave = tid >> 6;
    const int c16  = lane & 15;
    const int q    = lane >> 4;

    // ---- weight B-fragments in registers (loaded once per block) ----
    bf16x8 winf[6][2];
#pragma unroll
    for (int kk = 0; kk < 6; ++kk)
#pragma unroll
        for (int nt = 0; nt < 2; ++nt)
#pragma unroll
            for (int j = 0; j < 8; ++j)
                winf[kk][nt][j] =
                    (__bf16)W_in[(kk * 32 + q * 8 + j) * kIU + wave * 32 + nt * 16 + c16];
    bf16x8 woutf[4];
#pragma unroll
    for (int kk = 0; kk < 4; ++kk)
#pragma unroll
        for (int j = 0; j < 8; ++j)
            woutf[kk][j] = (__bf16)W_out[(kk * 32 + q * 8 + j) * kDN + wave * 16 + c16];
    bf16x8 wedgef[2];
#pragma unroll
    for (int kk = 0; kk < 2; ++kk)
#pragma unroll
        for (int j = 0; j < 8; ++j)
            wedgef[kk][j] = (__bf16)W_edge[(kk * 32 + q * 8 + j) * kDE + wave * 16 + c16];

    const float bin0 = b_in[wave * 32 + c16];
    const float bin1 = b_in[wave * 32 + 16 + c16];
    const float bo   = b_out[wave * 16 + c16];
    const float beg  = b_edge[wave * 16 + c16];

    const int row = tid >> 2;   // edge row within tile
    const int qt  = tid & 3;    // column-quarter owner
    const int ntiles = kBE / 64;
    const int stride = gridDim.x;

    int t = blockIdx.x;
    int rV, sV, rN, sN;
    bf16x8 R[2], Sd[2];         // recv/send node rows (bf16, 32B/lane)
    float4 Ee[4];               // edge row (fp32, 64B/lane)
    {
        const int g = t * 64 + row;
        rV = receivers[g]; sV = senders[g];
        const int b  = g >> 16;
        const int rg = (rV < 0) ? (kBN - 1) : rV + (b << 13);
        const int sg = (sV < 0) ? (kBN - 1) : sV + (b << 13);
        const bf16x8* nb = (const bf16x8*)nbf;
        R[0]  = nb[rg * 8 + qt * 2];  R[1]  = nb[rg * 8 + qt * 2 + 1];
        Sd[0] = nb[sg * 8 + qt * 2];  Sd[1] = nb[sg * 8 + qt * 2 + 1];
        const float4* ez = (const float4*)edges + (size_t)g * 16;
#pragma unroll
        for (int i = 0; i < 4; ++i) Ee[i] = ez[qt + 4 * i];
        const int t1 = (t + stride < ntiles) ? (t + stride) : t;
        const int g1 = t1 * 64 + row;
        rN = receivers[g1]; sN = senders[g1];
    }

    int buf = 0;
    for (; t < ntiles; t += stride) {
        const int g0 = t * 64;

        // ---- stage X + per-edge side effects ----
        {
            const int b  = (g0 + row) >> 16;
            const int rs = (rV < 0) ? -1 : rV + (b << 13);
            if (qt == 0) {
                rsS[buf][row] = rs;
                const int g = g0 + row;
                out_sf[g] = (float)sV;
                out_rf[g] = (float)rV;
                if (rs >= 0) atomicAdd(&counts[rs], 1.0f);
            }
            __bf16* xr = &Xs_[row * XS];
            // recv/send: pure b128 copies; bank group (row+2qt)%8 spreads
            // the wave across all 8 quad-bank groups.
            *(bf16x8*)&xr[qt * 16]           = R[0];
            *(bf16x8*)&xr[qt * 16 + 8]       = R[1];
            *(bf16x8*)&xr[128 + qt * 16]     = Sd[0];
            *(bf16x8*)&xr[128 + qt * 16 + 8] = Sd[1];
#pragma unroll
            for (int i = 0; i < 4; ++i) {
                float4 e = Ee[i];
                *(bf16x4*)&xr[64 + 4 * qt + 16 * i] =
                    (bf16x4){(__bf16)e.x, (__bf16)e.y, (__bf16)e.z, (__bf16)e.w};
            }
        }
        lds_barrier();   // B1: X ready

        // ---- prefetch gathers for t+stride, indices for t+2*stride ----
        {
            const int rG = rN, sG = sN;
            const int tn = (t + stride < ntiles) ? (t + stride) : t;
            const int gn = tn * 64 + row;
            const int b  = gn >> 16;
            const int rg = (rG < 0) ? (kBN - 1) : rG + (b << 13);
            const int sg = (sG < 0) ? (kBN - 1) : sG + (b << 13);
            const bf16x8* nb = (const bf16x8*)nbf;
            R[0]  = nb[rg * 8 + qt * 2];  R[1]  = nb[rg * 8 + qt * 2 + 1];
            Sd[0] = nb[sg * 8 + qt * 2];  Sd[1] = nb[sg * 8 + qt * 2 + 1];
            const float4* ez = (const float4*)edges + (size_t)gn * 16;
#pragma unroll
            for (int i = 0; i < 4; ++i) Ee[i] = ez[qt + 4 * i];
            const int t2 = (t + 2 * stride < ntiles) ? (t + 2 * stride) : tn;
            const int g2 = t2 * 64 + row;
            rN = receivers[g2]; sN = senders[g2];
            rV = rG; sV = sG;
        }

        // ---- layer 1: [64x192]@[192x128] -> H ----
#pragma unroll
        for (int m = 0; m < 4; ++m) {
            const __bf16* ar = &Xs_[(m * 16 + c16) * XS + q * 8];
            bf16x8 a[6];
#pragma unroll
            for (int kk = 0; kk < 6; ++kk) a[kk] = *(const bf16x8*)(ar + kk * 32);
            f32x4 acc0 = (f32x4){0.f,0.f,0.f,0.f}, acc1 = (f32x4){0.f,0.f,0.f,0.f};
#pragma unroll
            for (int kk = 0; kk < 6; ++kk)
                acc0 = __builtin_amdgcn_mfma_f32_16x16x32_bf16(a[kk], winf[kk][0], acc0, 0, 0, 0);
#pragma unroll
            for (int kk = 0; kk < 6; ++kk)
                acc1 = __builtin_amdgcn_mfma_f32_16x16x32_bf16(a[kk], winf[kk][1], acc1, 0, 0, 0);
#pragma unroll
            for (int r = 0; r < 4; ++r) {
                __bf16* hr = &Hs_[(m * 16 + q * 4 + r) * HS + wave * 32];
                hr[c16]      = (__bf16)fmaxf(acc0[r] + bin0, 0.f);
                hr[16 + c16] = (__bf16)fmaxf(acc1[r] + bin1, 0.f);
            }
        }
        lds_barrier();   // B2: H ready

        // ---- layer 2: [64x128]@[128x64] -> E (e_new) ----
#pragma unroll
        for (int m = 0; m < 4; ++m) {
            const __bf16* ar = &Hs_[(m * 16 + c16) * HS + q * 8];
            bf16x8 a[4];
#pragma unroll
            for (int kk = 0; kk < 4; ++kk) a[kk] = *(const bf16x8*)(ar + kk * 32);
            f32x4 acc = (f32x4){0.f,0.f,0.f,0.f};
#pragma unroll
            for (int kk = 0; kk < 4; ++kk)
                acc = __builtin_amdgcn_mfma_f32_16x16x32_bf16(a[kk], woutf[kk], acc, 0, 0, 0);
#pragma unroll
            for (int r = 0; r < 4; ++r)
                Es_[(m * 16 + q * 4 + r) * ES + wave * 16 + c16] = (__bf16)fmaxf(acc[r] + bo, 0.f);
        }
        lds_barrier();   // B3: E ready

        // ---- layer 3: [64x64]@[64x64] -> edges_out ----
#pragma unroll
        for (int m = 0; m < 4; ++m) {
            const __bf16* ar = &Es_[(m * 16 + c16) * ES + q * 8];
            bf16x8 a0 = *(const bf16x8*)ar;
            bf16x8 a1 = *(const bf16x8*)(ar + 32);
            f32x4 acc = (f32x4){0.f,0.f,0.f,0.f};
            acc = __builtin_amdgcn_mfma_f32_16x16x32_bf16(a0, wedgef[0], acc, 0, 0, 0);
            acc = __builtin_amdgcn_mfma_f32_16x16x32_bf16(a1, wedgef[1], acc, 0, 0, 0);
#pragma unroll
            for (int r = 0; r < 4; ++r)
                edges_out[(size_t)(g0 + m * 16 + q * 4 + r) * kDE + wave * 16 + c16] =
                    fmaxf(acc[r] + beg, 0.f);
        }

        // ---- scatter e_new -> bf16 sums via packed atomics ----
        {
            const int half = lane >> 5;
            const int pc   = lane & 31;
#pragma unroll
            for (int i = 0; i < 8; ++i) {
                const int rr = wave * 16 + half * 8 + i;
                const int rs = rsS[buf][rr];
                if (rs >= 0) {
                    const uint32_t pk = *(const uint32_t*)&Es_[rr * ES + pc * 2];
                    atomic_pk_add_bf16(sums + (size_t)rs * kDN + pc * 2, pk);
                }
            }
        }
        buf ^= 1;
    }
}

// nodes_new = counts>0 ? bf16sums/counts : 0  (1 thread = 4 columns)
__global__ __launch_bounds__(256)
void finalize_kernel(const unsigned int* __restrict__ sums_u32,  // 2 bf16 per u32
                     const float* __restrict__ counts,
                     float* __restrict__ out)
{
    const int t = blockIdx.x * blockDim.x + threadIdx.x;   // < kBN*kDN/4
    const unsigned int p0 = sums_u32[t * 2];
    const unsigned int p1 = sums_u32[t * 2 + 1];
    const float c = counts[t >> 4];
    float4 o;
    if (c > 0.f) {
        const float inv = 1.f / c;
        union { unsigned int u; float f; } v;
        v.u = p0 << 16;            o.x = v.f * inv;
        v.u = p0 & 0xffff0000u;    o.y = v.f * inv;
        v.u = p1 << 16;            o.z = v.f * inv;
        v.u = p1 & 0xffff0000u;    o.w = v.f * inv;
    } else {
        o.x = o.y = o.z = o.w = 0.f;
    }
    ((float4*)out)[t] = o;
}

extern "C" void kernel_launch(void* const* d_in, const int* in_sizes, int n_in,
                              void* d_out, int out_size, void* d_ws, size_t ws_size,
                              hipStream_t stream) {
    const float* nodes     = (const float*)d_in[0];
    const float* edges     = (const float*)d_in[1];
    const int*   senders   = (const int*)d_in[2];
    const int*   receivers = (const int*)d_in[3];
    const float* W_in      = (const float*)d_in[4];
    const float* b_in      = (const float*)d_in[5];
    const float* W_out     = (const float*)d_in[6];
    const float* b_out     = (const float*)d_in[7];
    const float* W_edge    = (const float*)d_in[8];
    const float* b_edge    = (const float*)d_in[9];

    float* out       = (float*)d_out;
    float* edges_out = out + (size_t)kBN * kDN;
    float* out_sf    = edges_out + (size_t)kBE * kDE;
    float* out_rf    = out_sf + kBE;

    // ws: bf16 sums [8 MiB] | fp32 counts [256 KiB]   (identical to baseline)
    __bf16* sums  = (__bf16*)d_ws;
    float* counts = (float*)((char*)d_ws + (size_t)kBN * kDN * 2);

    // bf16 node table (8 MiB) lives in the nodes_new output region (16 MiB),
    // which is dead until finalize_kernel overwrites it at the end.
    __bf16* nbf = (__bf16*)out;

    hipMemsetAsync(d_ws, 0, (size_t)kBN * kDN * 2 + (size_t)kBN * 4, stream);

    cast_nodes<<<kBN * kDN / 8 / 256, 256, 0, stream>>>(nodes, nbf);

    edge_mlp_pk<<<2048, 256, 0, stream>>>(
        nbf, edges, senders, receivers,
        W_in, b_in, W_out, b_out, W_edge, b_edge,
        edges_out, out_sf, out_rf, sums, counts);

    finalize_kernel<<<kBN * kDN / 4 / 256, 256, 0, stream>>>(
        (const unsigned int*)sums, counts, out);
}

// Round 6
// 335.285 us; speedup vs baseline: 1.2931x; 1.0000x over previous
//
#include <hip/hip_runtime.h>

typedef __attribute__((ext_vector_type(8))) __bf16 bf16x8;
typedef __attribute__((ext_vector_type(4))) __bf16 bf16x4;
typedef __attribute__((ext_vector_type(4))) float f32x4;

constexpr int kB = 8, kN = 8192, kE = 65536;
constexpr int kBN = kB * kN;    // 65536 nodes total
constexpr int kBE = kB * kE;    // 524288 edges total
constexpr int kDN = 64, kDE = 64, kIU = 128;

constexpr int XS = 200;  // X row stride in bf16 (192 + 8 pad)
constexpr int HS = 136;  // H row stride (128 + 8)
constexpr int ES = 72;   // E row stride (64 + 8)

// LDS-only barrier: leaves global loads/stores/atomics outstanding across it.
__device__ __forceinline__ void lds_barrier() {
    asm volatile("s_waitcnt lgkmcnt(0)\n\ts_barrier" ::: "memory");
}

// Packed bf16x2 atomic add (device scope via sc1). addr first, data second.
__device__ __forceinline__ void atomic_pk_add_bf16(__bf16* p, uint32_t pk) {
    const unsigned long long a64 = (unsigned long long)p;
    asm volatile("global_atomic_pk_add_bf16 %0, %1, off sc1"
                 :: "v"(a64), "v"(pk) : "memory");
}

// ---------------------------------------------------------------------------
// Pre-pass: cast fp32 node table -> bf16 (halves gather bytes + L2 footprint).
// Streaming in/out marked non-temporal (via clang ext_vector f32x4 — HIP's
// float4 class type is rejected by the builtin).
// ---------------------------------------------------------------------------
__global__ __launch_bounds__(256)
void cast_nodes(const float* __restrict__ nodes, __bf16* __restrict__ nbf) {
    const int t = blockIdx.x * 256 + threadIdx.x;      // < kBN*kDN/8
    const f32x4* nf = (const f32x4*)nodes;
    const f32x4 a = __builtin_nontemporal_load(nf + t * 2);
    const f32x4 c = __builtin_nontemporal_load(nf + t * 2 + 1);
    bf16x8 o = {(__bf16)a.x, (__bf16)a.y, (__bf16)a.z, (__bf16)a.w,
                (__bf16)c.x, (__bf16)c.y, (__bf16)c.z, (__bf16)c.w};
    __builtin_nontemporal_store(o, (bf16x8*)nbf + t);
}

// ---------------------------------------------------------------------------
// Fused edge MLP: gather -> L1 -> L2 (e_new) -> L3 (edges_out)
//   e_new scattered into bf16 sums table via packed-bf16 atomics (2 cols/op).
//   Write-once streams (edges_out, sf, rf) are NON-TEMPORAL so they don't
//   wash the sums/nbf/edges working set (~150 MB) out of the 256 MB IF$ —
//   keeps the atomic RMW target lines cache-resident (round-3 counters showed
//   ~79 MB of HBM churn from evicted sums lines).
// ---------------------------------------------------------------------------
__global__ __launch_bounds__(256, 3)
void edge_mlp_pk(const __bf16* __restrict__ nbf,
                 const float* __restrict__ edges,
                 const int* __restrict__ senders,
                 const int* __restrict__ receivers,
                 const float* __restrict__ W_in,
                 const float* __restrict__ b_in,
                 const float* __restrict__ W_out,
                 const float* __restrict__ b_out,
                 const float* __restrict__ W_edge,
                 const float* __restrict__ b_edge,
                 float* __restrict__ edges_out,
                 float* __restrict__ out_sf,
                 float* __restrict__ out_rf,
                 __bf16* __restrict__ sums,     // [kBN][64] bf16
                 float* __restrict__ counts)    // [kBN] fp32
{
    __shared__ alignas(16) __bf16 Xs_[64 * XS];
    __shared__ alignas(16) __bf16 Hs_[64 * HS];
    __shared__ alignas(16) __bf16 Es_[64 * ES];
    __shared__ int rsS[2][64];

    const int tid  = threadIdx.x;
    const int lane = tid & 63;
    const int wave = tid >> 6;
    const int c16  = lane & 15;
    const int q    = lane >> 4;

    // ---- weight B-fragments in registers (loaded once per block) ----
    bf16x8 winf[6][2];
#pragma unroll
    for (int kk = 0; kk < 6; ++kk)
#pragma unroll
        for (int nt = 0; nt < 2; ++nt)
#pragma unroll
            for (int j = 0; j < 8; ++j)
                winf[kk][nt][j] =
                    (__bf16)W_in[(kk * 32 + q * 8 + j) * kIU + wave * 32 + nt * 16 + c16];
    bf16x8 woutf[4];
#pragma unroll
    for (int kk = 0; kk < 4; ++kk)
#pragma unroll
        for (int j = 0; j < 8; ++j)
            woutf[kk][j] = (__bf16)W_out[(kk * 32 + q * 8 + j) * kDN + wave * 16 + c16];
    bf16x8 wedgef[2];
#pragma unroll
    for (int kk = 0; kk < 2; ++kk)
#pragma unroll
        for (int j = 0; j < 8; ++j)
            wedgef[kk][j] = (__bf16)W_edge[(kk * 32 + q * 8 + j) * kDE + wave * 16 + c16];

    const float bin0 = b_in[wave * 32 + c16];
    const float bin1 = b_in[wave * 32 + 16 + c16];
    const float bo   = b_out[wave * 16 + c16];
    const float beg  = b_edge[wave * 16 + c16];

    const int row = tid >> 2;   // edge row within tile
    const int qt  = tid & 3;    // column-quarter owner
    const int ntiles = kBE / 64;
    const int stride = gridDim.x;

    int t = blockIdx.x;
    int rV, sV, rN, sN;
    bf16x8 R[2], Sd[2];         // recv/send node rows (bf16, 32B/lane)
    f32x4 Ee[4];                // edge row (fp32, 64B/lane)
    {
        const int g = t * 64 + row;
        rV = receivers[g]; sV = senders[g];
        const int b  = g >> 16;
        const int rg = (rV < 0) ? (kBN - 1) : rV + (b << 13);
        const int sg = (sV < 0) ? (kBN - 1) : sV + (b << 13);
        const bf16x8* nb = (const bf16x8*)nbf;
        R[0]  = nb[rg * 8 + qt * 2];  R[1]  = nb[rg * 8 + qt * 2 + 1];
        Sd[0] = nb[sg * 8 + qt * 2];  Sd[1] = nb[sg * 8 + qt * 2 + 1];
        const f32x4* ez = (const f32x4*)edges + (size_t)g * 16;
#pragma unroll
        for (int i = 0; i < 4; ++i) Ee[i] = ez[qt + 4 * i];
        const int t1 = (t + stride < ntiles) ? (t + stride) : t;
        const int g1 = t1 * 64 + row;
        rN = receivers[g1]; sN = senders[g1];
    }

    int buf = 0;
    for (; t < ntiles; t += stride) {
        const int g0 = t * 64;

        // ---- stage X + per-edge side effects ----
        {
            const int b  = (g0 + row) >> 16;
            const int rs = (rV < 0) ? -1 : rV + (b << 13);
            if (qt == 0) {
                rsS[buf][row] = rs;
                const int g = g0 + row;
                __builtin_nontemporal_store((float)sV, &out_sf[g]);
                __builtin_nontemporal_store((float)rV, &out_rf[g]);
                if (rs >= 0) atomicAdd(&counts[rs], 1.0f);
            }
            __bf16* xr = &Xs_[row * XS];
            // recv/send: pure b128 copies; bank group (row+2qt)%8 spreads
            // the wave across all 8 quad-bank groups.
            *(bf16x8*)&xr[qt * 16]           = R[0];
            *(bf16x8*)&xr[qt * 16 + 8]       = R[1];
            *(bf16x8*)&xr[128 + qt * 16]     = Sd[0];
            *(bf16x8*)&xr[128 + qt * 16 + 8] = Sd[1];
#pragma unroll
            for (int i = 0; i < 4; ++i) {
                f32x4 e = Ee[i];
                *(bf16x4*)&xr[64 + 4 * qt + 16 * i] =
                    (bf16x4){(__bf16)e.x, (__bf16)e.y, (__bf16)e.z, (__bf16)e.w};
            }
        }
        lds_barrier();   // B1: X ready

        // ---- prefetch gathers for t+stride, indices for t+2*stride ----
        {
            const int rG = rN, sG = sN;
            const int tn = (t + stride < ntiles) ? (t + stride) : t;
            const int gn = tn * 64 + row;
            const int b  = gn >> 16;
            const int rg = (rG < 0) ? (kBN - 1) : rG + (b << 13);
            const int sg = (sG < 0) ? (kBN - 1) : sG + (b << 13);
            const bf16x8* nb = (const bf16x8*)nbf;
            R[0]  = nb[rg * 8 + qt * 2];  R[1]  = nb[rg * 8 + qt * 2 + 1];
            Sd[0] = nb[sg * 8 + qt * 2];  Sd[1] = nb[sg * 8 + qt * 2 + 1];
            const f32x4* ez = (const f32x4*)edges + (size_t)gn * 16;
#pragma unroll
            for (int i = 0; i < 4; ++i) Ee[i] = ez[qt + 4 * i];
            const int t2 = (t + 2 * stride < ntiles) ? (t + 2 * stride) : tn;
            const int g2 = t2 * 64 + row;
            rN = receivers[g2]; sN = senders[g2];
            rV = rG; sV = sG;
        }

        // ---- layer 1: [64x192]@[192x128] -> H ----
#pragma unroll
        for (int m = 0; m < 4; ++m) {
            const __bf16* ar = &Xs_[(m * 16 + c16) * XS + q * 8];
            bf16x8 a[6];
#pragma unroll
            for (int kk = 0; kk < 6; ++kk) a[kk] = *(const bf16x8*)(ar + kk * 32);
            f32x4 acc0 = (f32x4){0.f,0.f,0.f,0.f}, acc1 = (f32x4){0.f,0.f,0.f,0.f};
#pragma unroll
            for (int kk = 0; kk < 6; ++kk)
                acc0 = __builtin_amdgcn_mfma_f32_16x16x32_bf16(a[kk], winf[kk][0], acc0, 0, 0, 0);
#pragma unroll
            for (int kk = 0; kk < 6; ++kk)
                acc1 = __builtin_amdgcn_mfma_f32_16x16x32_bf16(a[kk], winf[kk][1], acc1, 0, 0, 0);
#pragma unroll
            for (int r = 0; r < 4; ++r) {
                __bf16* hr = &Hs_[(m * 16 + q * 4 + r) * HS + wave * 32];
                hr[c16]      = (__bf16)fmaxf(acc0[r] + bin0, 0.f);
                hr[16 + c16] = (__bf16)fmaxf(acc1[r] + bin1, 0.f);
            }
        }
        lds_barrier();   // B2: H ready

        // ---- layer 2: [64x128]@[128x64] -> E (e_new) ----
#pragma unroll
        for (int m = 0; m < 4; ++m) {
            const __bf16* ar = &Hs_[(m * 16 + c16) * HS + q * 8];
            bf16x8 a[4];
#pragma unroll
            for (int kk = 0; kk < 4; ++kk) a[kk] = *(const bf16x8*)(ar + kk * 32);
            f32x4 acc = (f32x4){0.f,0.f,0.f,0.f};
#pragma unroll
            for (int kk = 0; kk < 4; ++kk)
                acc = __builtin_amdgcn_mfma_f32_16x16x32_bf16(a[kk], woutf[kk], acc, 0, 0, 0);
#pragma unroll
            for (int r = 0; r < 4; ++r)
                Es_[(m * 16 + q * 4 + r) * ES + wave * 16 + c16] = (__bf16)fmaxf(acc[r] + bo, 0.f);
        }
        lds_barrier();   // B3: E ready

        // ---- layer 3: [64x64]@[64x64] -> edges_out (non-temporal) ----
#pragma unroll
        for (int m = 0; m < 4; ++m) {
            const __bf16* ar = &Es_[(m * 16 + c16) * ES + q * 8];
            bf16x8 a0 = *(const bf16x8*)ar;
            bf16x8 a1 = *(const bf16x8*)(ar + 32);
            f32x4 acc = (f32x4){0.f,0.f,0.f,0.f};
            acc = __builtin_amdgcn_mfma_f32_16x16x32_bf16(a0, wedgef[0], acc, 0, 0, 0);
            acc = __builtin_amdgcn_mfma_f32_16x16x32_bf16(a1, wedgef[1], acc, 0, 0, 0);
#pragma unroll
            for (int r = 0; r < 4; ++r)
                __builtin_nontemporal_store(
                    fmaxf(acc[r] + beg, 0.f),
                    &edges_out[(size_t)(g0 + m * 16 + q * 4 + r) * kDE + wave * 16 + c16]);
        }

        // ---- scatter e_new -> bf16 sums via packed atomics ----
        {
            const int half = lane >> 5;
            const int pc   = lane & 31;
#pragma unroll
            for (int i = 0; i < 8; ++i) {
                const int rr = wave * 16 + half * 8 + i;
                const int rs = rsS[buf][rr];
                if (rs >= 0) {
                    const uint32_t pk = *(const uint32_t*)&Es_[rr * ES + pc * 2];
                    atomic_pk_add_bf16(sums + (size_t)rs * kDN + pc * 2, pk);
                }
            }
        }
        buf ^= 1;
    }
}

// nodes_new = counts>0 ? bf16sums/counts : 0  (1 thread = 4 columns)
__global__ __launch_bounds__(256)
void finalize_kernel(const unsigned int* __restrict__ sums_u32,  // 2 bf16 per u32
                     const float* __restrict__ counts,
                     float* __restrict__ out)
{
    const int t = blockIdx.x * blockDim.x + threadIdx.x;   // < kBN*kDN/4
    const unsigned int p0 = sums_u32[t * 2];
    const unsigned int p1 = sums_u32[t * 2 + 1];
    const float c = counts[t >> 4];
    f32x4 o;
    if (c > 0.f) {
        const float inv = 1.f / c;
        union { unsigned int u; float f; } v;
        v.u = p0 << 16;            o.x = v.f * inv;
        v.u = p0 & 0xffff0000u;    o.y = v.f * inv;
        v.u = p1 << 16;            o.z = v.f * inv;
        v.u = p1 & 0xffff0000u;    o.w = v.f * inv;
    } else {
        o = (f32x4){0.f, 0.f, 0.f, 0.f};
    }
    __builtin_nontemporal_store(o, (f32x4*)out + t);
}

extern "C" void kernel_launch(void* const* d_in, const int* in_sizes, int n_in,
                              void* d_out, int out_size, void* d_ws, size_t ws_size,
                              hipStream_t stream) {
    const float* nodes     = (const float*)d_in[0];
    const float* edges     = (const float*)d_in[1];
    const int*   senders   = (const int*)d_in[2];
    const int*   receivers = (const int*)d_in[3];
    const float* W_in      = (const float*)d_in[4];
    const float* b_in      = (const float*)d_in[5];
    const float* W_out     = (const float*)d_in[6];
    const float* b_out     = (const float*)d_in[7];
    const float* W_edge    = (const float*)d_in[8];
    const float* b_edge    = (const float*)d_in[9];

    float* out       = (float*)d_out;
    float* edges_out = out + (size_t)kBN * kDN;
    float* out_sf    = edges_out + (size_t)kBE * kDE;
    float* out_rf    = out_sf + kBE;

    // ws: bf16 sums [8 MiB] | fp32 counts [256 KiB]   (identical to baseline)
    __bf16* sums  = (__bf16*)d_ws;
    float* counts = (float*)((char*)d_ws + (size_t)kBN * kDN * 2);

    // bf16 node table (8 MiB) lives in the nodes_new output region (16 MiB),
    // which is dead until finalize_kernel overwrites it at the end.
    __bf16* nbf = (__bf16*)out;

    (void)hipMemsetAsync(d_ws, 0, (size_t)kBN * kDN * 2 + (size_t)kBN * 4, stream);

    cast_nodes<<<kBN * kDN / 8 / 256, 256, 0, stream>>>(nodes, nbf);

    edge_mlp_pk<<<2048, 256, 0, stream>>>(
        nbf, edges, senders, receivers,
        W_in, b_in, W_out, b_out, W_edge, b_edge,
        edges_out, out_sf, out_rf, sums, counts);

    finalize_kernel<<<kBN * kDN / 4 / 256, 256, 0, stream>>>(
        (const unsigned int*)sums, counts, out);
}